// Round 2
// baseline (18889.140 us; speedup 1.0000x reference)
//
#include <hip/hip_runtime.h>
#include <math.h>

#define NB 512
#define NT 256
#define BB 64
#define TT 32
#define ENCL 128
#define DD 800
#define BD (BB * DD)
#define KC 8

__device__ __forceinline__ float sigf(float x) { return 1.0f / (1.0f + __expf(-x)); }

__device__ __forceinline__ float wred(float v) {
#pragma unroll
    for (int off = 32; off > 0; off >>= 1) v += __shfl_xor(v, off);
    return v;
}

union SMEM {
    struct { float A[64 * 204]; } g;                 // 52224 B (GEMM staging)
    struct { float cin[DD]; float h[DD]; float c[DD]; float hn[DD];
             float cw[1536]; float cb[32]; } ph;     // cell + scores
    struct { float p[128]; float red[256]; } p2;     // softmax + ctx
    struct { float hv[DD]; float sc[64]; float sp[64]; } p3; // reduce + self attn
};

__device__ __forceinline__ void gbar(unsigned* cnt, unsigned target) {
    __syncthreads();
    if (threadIdx.x == 0) {
        __hip_atomic_fetch_add(cnt, 1u, __ATOMIC_RELEASE, __HIP_MEMORY_SCOPE_AGENT);
        while (__hip_atomic_load(cnt, __ATOMIC_RELAXED, __HIP_MEMORY_SCOPE_AGENT) < target)
            __builtin_amdgcn_s_sleep(2);
        __builtin_amdgcn_fence(__ATOMIC_ACQUIRE, "agent");
    }
    __syncthreads();
}

__device__ __forceinline__ void gemm_phase(int bid, int tid, const float* __restrict__ A1,
                                           const float* __restrict__ A2, const float* __restrict__ W,
                                           float* __restrict__ PB, SMEM& u) {
    if (bid >= 200) return;
    const int kc = bid & 7;
    const int dt = bid >> 3;
    const float* src = (kc < 4) ? A1 : A2;
    const int koff = (kc & 3) * 200;
    for (int i = tid; i < 64 * 200; i += NT) {
        int bb = i / 200, kk = i - bb * 200;
        u.g.A[bb * 204 + kk] = src[bb * DD + koff + kk];
    }
    __syncthreads();
    const int d16 = tid & 15;
    const int bq = tid >> 4;
    const int c0 = dt * 32 + d16;
    float acc[4][2] = {};
    const float* W0 = W + (size_t)(kc * 200) * DD;
    for (int kk = 0; kk < 200; kk += 4) {
        float wA[4], wB[4];
#pragma unroll
        for (int p = 0; p < 4; ++p) {
            wA[p] = W0[(size_t)(kk + p) * DD + c0];
            wB[p] = W0[(size_t)(kk + p) * DD + c0 + 16];
        }
#pragma unroll
        for (int rr = 0; rr < 4; ++rr) {
            const float4 a4 = *reinterpret_cast<const float4*>(&u.g.A[(bq * 4 + rr) * 204 + kk]);
            acc[rr][0] = fmaf(a4.x, wA[0], fmaf(a4.y, wA[1], fmaf(a4.z, wA[2], fmaf(a4.w, wA[3], acc[rr][0]))));
            acc[rr][1] = fmaf(a4.x, wB[0], fmaf(a4.y, wB[1], fmaf(a4.z, wB[2], fmaf(a4.w, wB[3], acc[rr][1]))));
        }
    }
#pragma unroll
    for (int rr = 0; rr < 4; ++rr) {
        int bb = bq * 4 + rr;
        PB[(size_t)(kc * BB + bb) * DD + c0] = acc[rr][0];
        PB[(size_t)(kc * BB + bb) * DD + c0 + 16] = acc[rr][1];
    }
}

__global__ __launch_bounds__(NT, 2) void persistent_kernel(
    const float* __restrict__ x, const float* __restrict__ enc,
    float* __restrict__ Hbuf, float* __restrict__ Cbuf,
    float* __restrict__ PRE, float* __restrict__ REF,
    float* __restrict__ CTX, float* __restrict__ HV1,
    float* __restrict__ SCI, float* __restrict__ PB, unsigned* cnt,
    const float* __restrict__ cw0, const float* __restrict__ cb0,
    const float* __restrict__ cw1, const float* __restrict__ cb1,
    const float* __restrict__ iw0, const float* __restrict__ ib0,
    const float* __restrict__ iw1, const float* __restrict__ ib1,
    const float* __restrict__ sw0, const float* __restrict__ sb0,
    const float* __restrict__ sw1, const float* __restrict__ sb1)
{
    __shared__ SMEM u;
    const int bid = blockIdx.x;
    const int tid = threadIdx.x;
    const int lane = tid & 63;
    const int wv = tid >> 6;
    const int b = bid & 63;
    const int j = bid >> 6;   // 0..7 sub-block within batch group

    const float* cwA[2] = {cw0, cw1};
    const float* cbA[2] = {cb0, cb1};
    const float* iwA[2] = {iw0, iw1};
    const float* ibA[2] = {ib0, ib1};
    const float* swA[2] = {sw0, sw1};
    const float* sbA[2] = {sb0, sb1};

    unsigned bar_n = 0;

    for (int s = 0; s < TT; ++s) {
        const float* Hr = Hbuf + (size_t)(s & 1) * 2 * BD;
        float* Hw = Hbuf + (size_t)((s & 1) ^ 1) * 2 * BD;
        const float* Cr = Cbuf + (size_t)(s & 1) * 2 * BD;
        float* Cw = Cbuf + (size_t)((s & 1) ^ 1) * 2 * BD;

        for (int l = 0; l < 2; ++l) {
            const int cinx = (l == 0) ? 1 : 8;
            const int cin = cinx + 8;
            // ===== PH1: deferred REF write, cell input, cell, inter scores =====
            {
                // (a) materialize REF[1][s-1] from gemm2(s-1,1) partials (slice j)
                if (l == 0 && s >= 2) {
                    for (int i = tid; i < 100; i += NT) {
                        int col = j * 100 + i;
                        float sum = sb1[col];
#pragma unroll
                        for (int kc = 0; kc < KC; ++kc) sum += PB[(size_t)(kc * BB + b) * DD + col];
                        REF[((size_t)TT + (s - 1)) * BD + (size_t)b * DD + col] = tanhf(sum);
                    }
                }
                // (b) cell input into LDS
                if (l == 0) {
                    for (int i = tid; i < 100; i += NT) u.ph.cin[i] = x[(b * TT + s) * 100 + i];
                } else if (s == 0) {
                    for (int i = tid; i < DD; i += NT) u.ph.cin[i] = REF[(size_t)b * DD + i];
                } else {
                    for (int i = tid; i < DD; i += NT) {
                        float sum = sb0[i];
#pragma unroll
                        for (int kc = 0; kc < KC; ++kc) sum += PB[(size_t)(kc * BB + b) * DD + i];
                        float v = tanhf(sum);
                        u.ph.cin[i] = v;
                        if ((unsigned)(i - j * 100) < 100u)
                            REF[(size_t)s * BD + (size_t)b * DD + i] = v;  // REF[0][s]
                    }
                }
                // (c) stage h_old, c_old, conv weights (transposed layout [ch][ic][gt][p])
                const float* hO = Hr + (size_t)l * BD + (size_t)b * DD;
                const float* cO = Cr + (size_t)l * BD + (size_t)b * DD;
                for (int i = tid; i < DD; i += NT) { u.ph.h[i] = hO[i]; u.ph.c[i] = cO[i]; }
                const float* cwp = cwA[l];
                const int nw = 32 * cin * 3;
                for (int i = tid; i < nw; i += NT) {
                    int p = i % 3, rest = i / 3;
                    int gt = rest & 3, rest2 = rest >> 2;
                    int ic = rest2 % cin, ch = rest2 / cin;
                    u.ph.cw[i] = cwp[((gt * 8 + ch) * cin + ic) * 3 + p];
                }
                if (tid < 32) u.ph.cb[tid] = cbA[l][tid];
                __syncthreads();
                // (d) cell: full row (redundant across j), write global slice j
                float* Hwr = Hw + (size_t)l * BD + (size_t)b * DD;
                float* Cwr = Cw + (size_t)l * BD + (size_t)b * DD;
                for (int i = tid; i < DD; i += NT) {
                    int col = i % 10, rch = i / 10;
                    int ch = rch & 7, r = rch >> 3;
                    float g0 = u.ph.cb[ch], g1 = u.ph.cb[8 + ch], g2 = u.ph.cb[16 + ch], g3 = u.ph.cb[24 + ch];
                    for (int ic = 0; ic < cin; ++ic) {
                        const float* zb;
                        if (ic < cinx) zb = (l == 0) ? &u.ph.cin[r * 10] : &u.ph.cin[r * 80 + ic * 10];
                        else zb = &u.ph.h[r * 80 + (ic - cinx) * 10];
                        float z0 = (col > 0) ? zb[col - 1] : 0.f;
                        float z1 = zb[col];
                        float z2 = (col < 9) ? zb[col + 1] : 0.f;
                        const float* wr = &u.ph.cw[(ch * cin + ic) * 12];
                        g0 += z0 * wr[0] + z1 * wr[1] + z2 * wr[2];
                        g1 += z0 * wr[3] + z1 * wr[4] + z2 * wr[5];
                        g2 += z0 * wr[6] + z1 * wr[7] + z2 * wr[8];
                        g3 += z0 * wr[9] + z1 * wr[10] + z2 * wr[11];
                    }
                    float c2 = sigf(g1) * u.ph.c[i] + sigf(g0) * tanhf(g2);
                    float hn = sigf(g3) * tanhf(c2);
                    u.ph.hn[i] = hn;
                    if ((unsigned)(i - j * 100) < 100u) { Hwr[i] = hn; Cwr[i] = c2; }
                }
                __syncthreads();
                // (e) inter-attention scores: 16 encoder rows per block
                for (int lel = wv; lel < 16; lel += 4) {
                    int le = j * 16 + lel;
                    const float* er = enc + ((size_t)b * ENCL + le) * DD;
                    float sum = 0.f;
                    for (int k = lane; k < DD; k += 64) sum += u.ph.hn[k] * er[k];
                    sum = wred(sum);
                    if (lane == 0) SCI[b * ENCL + le] = sum;
                }
            }
            bar_n += NB; gbar(cnt, bar_n);
            // ===== PH2: softmax (redundant) + ctx slice =====
            {
                if (tid < 64) {
                    float v0 = SCI[b * ENCL + tid], v1 = SCI[b * ENCL + 64 + tid];
                    float m = fmaxf(v0, v1);
#pragma unroll
                    for (int off = 32; off > 0; off >>= 1) m = fmaxf(m, __shfl_xor(m, off));
                    float e0 = __expf(v0 - m), e1 = __expf(v1 - m);
                    float ss = e0 + e1;
                    ss = wred(ss);
                    float inv = 1.f / ss;
                    u.p2.p[tid] = e0 * inv;
                    u.p2.p[64 + tid] = e1 * inv;
                }
                __syncthreads();
                if (tid < 200) {
                    int d = j * 100 + (tid % 100);
                    int half = tid / 100;
                    const float* eb = enc + (size_t)b * ENCL * DD + (size_t)half * 64 * DD + d;
                    float sum = 0.f;
                    for (int le = 0; le < 64; ++le) sum += u.p2.p[half * 64 + le] * eb[(size_t)le * DD];
                    u.p2.red[tid] = sum;
                }
                __syncthreads();
                if (tid < 100) CTX[(size_t)b * DD + j * 100 + tid] = u.p2.red[tid] + u.p2.red[tid + 100];
            }
            bar_n += NB; gbar(cnt, bar_n);
            // ===== GEMM1: cat(ctx, h_new) @ iw =====
            gemm_phase(bid, tid, CTX, Hw + (size_t)l * BD, iwA[l], PB, u);
            bar_n += NB; gbar(cnt, bar_n);
            // ===== PH3: reduce+tanh -> hv1, PRE write; self-attn =====
            {
                const float* ibp = ibA[l];
                for (int i = tid; i < DD; i += NT) {
                    float sum = ibp[i];
#pragma unroll
                    for (int kc = 0; kc < KC; ++kc) sum += PB[(size_t)(kc * BB + b) * DD + i];
                    u.p3.hv[i] = tanhf(sum);
                }
                __syncthreads();
                if (tid < 100) {
                    int col = j * 100 + tid;
                    float v = u.p3.hv[col];
                    PRE[((size_t)l * TT + s) * BD + (size_t)b * DD + col] = v;
                    if (s == 0) REF[((size_t)l * TT) * BD + (size_t)b * DD + col] = v;
                    else HV1[(size_t)b * DD + col] = v;
                }
                if (s > 0) {
                    for (int t = wv; t < s; t += 4) {
                        const float* pr = PRE + ((size_t)l * TT + t) * BD + (size_t)b * DD;
                        float sum = 0.f;
                        for (int k = lane; k < DD; k += 64) sum += u.p3.hv[k] * pr[k];
                        sum = wred(sum);
                        if (lane == 0) u.p3.sc[t] = sum;
                    }
                    __syncthreads();
                    if (tid < 64) {
                        float v = (tid < s) ? u.p3.sc[tid] : -3.0e38f;
                        float m = v;
#pragma unroll
                        for (int off = 32; off > 0; off >>= 1) m = fmaxf(m, __shfl_xor(m, off));
                        float e = (tid < s) ? __expf(v - m) : 0.f;
                        float ss = wred(e);
                        u.p3.sp[tid] = e / ss;
                    }
                    __syncthreads();
                    if (tid < 100) {
                        int d = j * 100 + tid;
                        float sum = 0.f;
                        for (int t = 0; t < s; ++t)
                            sum += u.p3.sp[t] * REF[((size_t)l * TT + t) * BD + (size_t)b * DD + d];
                        CTX[(size_t)b * DD + d] = sum;   // CTX reused as ctx2 (GEMM1 already consumed it)
                    }
                }
            }
            bar_n += NB; gbar(cnt, bar_n);
            if (s > 0) {
                // ===== GEMM2: cat(ctx2, hv1) @ sw =====
                gemm_phase(bid, tid, CTX, HV1, swA[l], PB, u);
                bar_n += NB; gbar(cnt, bar_n);
            }
        }
    }
    // ===== final: materialize REF[1][31] from gemm2(31,1) partials =====
    if (tid < 100) {
        int col = j * 100 + tid;
        float sum = sb1[col];
#pragma unroll
        for (int kc = 0; kc < KC; ++kc) sum += PB[(size_t)(kc * BB + b) * DD + col];
        REF[((size_t)TT + 31) * BD + (size_t)b * DD + col] = tanhf(sum);
    }
}

// head layer 1: [2048,800] @ [800,200] + relu
__global__ __launch_bounds__(256) void head_a(const float* __restrict__ R1,
    const float* __restrict__ w1, const float* __restrict__ b1, float* __restrict__ V1)
{
    int g = blockIdx.x * 256 + threadIdx.x;      // 0 .. 204799
    int row = g / 200, col = g - row * 200;
    const float* a0 = R1 + (size_t)row * DD;
    const float* a1 = a0 + (size_t)1024 * DD;
    float s0 = b1[col], s1 = s0;
    for (int k = 0; k < DD; ++k) {
        float w = w1[k * 200 + col];
        s0 = fmaf(a0[k], w, s0);
        s1 = fmaf(a1[k], w, s1);
    }
    V1[(size_t)row * 200 + col] = fmaxf(s0, 0.f);
    V1[(size_t)(row + 1024) * 200 + col] = fmaxf(s1, 0.f);
}

// head layers 2+3: [2048,200]@[200,50]+relu, [2048,50]@[50,3]
__global__ __launch_bounds__(256) void head_b(const float* __restrict__ V1,
    const float* __restrict__ w2, const float* __restrict__ b2,
    const float* __restrict__ w3, const float* __restrict__ b3, float* __restrict__ out)
{
    __shared__ float v1[32][200];
    __shared__ float v2[32][50];
    int r0 = blockIdx.x * 32;
    for (int i = threadIdx.x; i < 32 * 200; i += 256) {
        int r = i / 200, c = i - r * 200;
        v1[r][c] = V1[(size_t)(r0 + r) * 200 + c];
    }
    __syncthreads();
    for (int i = threadIdx.x; i < 32 * 50; i += 256) {
        int r = i / 50, c = i - r * 50;
        float sum = b2[c];
        for (int k = 0; k < 200; ++k) sum = fmaf(v1[r][k], w2[k * 50 + c], sum);
        v2[r][c] = fmaxf(sum, 0.f);
    }
    __syncthreads();
    for (int i = threadIdx.x; i < 32 * 3; i += 256) {
        int r = i / 3, o = i - r * 3;
        float sum = b3[o];
        for (int k = 0; k < 50; ++k) sum = fmaf(v2[r][k], w3[k * 3 + o], sum);
        int row = r0 + r;
        int bb = row & 63, t = row >> 6;
        out[(bb * TT + t) * 3 + o] = sum;
    }
}

extern "C" void kernel_launch(void* const* d_in, const int* in_sizes, int n_in,
                              void* d_out, int out_size, void* d_ws, size_t ws_size,
                              hipStream_t stream)
{
    const float* x_flat = (const float*)d_in[0];
    const float* enc    = (const float*)d_in[1];
    const float* init_h = (const float*)d_in[2];
    const float* init_c = (const float*)d_in[3];
    const float* cw0 = (const float*)d_in[4];
    const float* cb0 = (const float*)d_in[5];
    const float* cw1 = (const float*)d_in[6];
    const float* cb1 = (const float*)d_in[7];
    const float* iw0 = (const float*)d_in[8];
    const float* ib0 = (const float*)d_in[9];
    const float* iw1 = (const float*)d_in[10];
    const float* ib1 = (const float*)d_in[11];
    const float* sw0 = (const float*)d_in[12];
    const float* sb0 = (const float*)d_in[13];
    const float* sw1 = (const float*)d_in[14];
    const float* sb1 = (const float*)d_in[15];
    const float* hw1 = (const float*)d_in[16];
    const float* hb1 = (const float*)d_in[17];
    const float* hw2 = (const float*)d_in[18];
    const float* hb2 = (const float*)d_in[19];
    const float* hw3 = (const float*)d_in[20];
    const float* hb3 = (const float*)d_in[21];
    float* out = (float*)d_out;

    unsigned* cnt = (unsigned*)d_ws;
    float* base = (float*)((char*)d_ws + 256);
    float* Hbuf = base;                              // [2][2][BD]
    float* Cbuf = Hbuf + 4 * (size_t)BD;             // [2][2][BD]
    float* PRE  = Cbuf + 4 * (size_t)BD;             // [2][32][BD]
    float* REF  = PRE + 2 * (size_t)TT * BD;         // [2][32][BD]
    float* CTX  = REF + 2 * (size_t)TT * BD;         // [BD]
    float* HV1  = CTX + (size_t)BD;                  // [BD]
    float* SCI  = HV1 + (size_t)BD;                  // [64*128]
    float* PB   = SCI + 8192;                        // [8][BD] (reused as V1 by head)

    hipMemsetAsync(d_ws, 0, 256, stream);
    hipMemcpyAsync(Hbuf, init_h, 2 * (size_t)BD * sizeof(float), hipMemcpyDeviceToDevice, stream);
    hipMemcpyAsync(Cbuf, init_c, 2 * (size_t)BD * sizeof(float), hipMemcpyDeviceToDevice, stream);

    persistent_kernel<<<NB, NT, 0, stream>>>(
        x_flat, enc, Hbuf, Cbuf, PRE, REF, CTX, HV1, SCI, PB, cnt,
        cw0, cb0, cw1, cb1, iw0, ib0, iw1, ib1, sw0, sb0, sw1, sb1);

    head_a<<<800, 256, 0, stream>>>(REF + (size_t)TT * BD, hw1, hb1, PB);
    head_b<<<64, 256, 0, stream>>>(PB, hw2, hb2, hw3, hb3, out);
}